// Round 9
// baseline (363.932 us; speedup 1.0000x reference)
//
#include <hip/hip_runtime.h>

#define D 64
#define CHUNK 8192          // edges per partition block
#define BKT_SHIFT 10        // 1024 nodes per bucket
#define BKT_NODES 1024

// ---- misc ------------------------------------------------------------------

__global__ void zero_int(int* __restrict__ p, int n) {
    int i = blockIdx.x * blockDim.x + threadIdx.x;
    if (i < n) p[i] = 0;
}

// ---- level-1: bucket histogram of dst>>BKT_SHIFT ---------------------------

__global__ void bucket_hist(const int* __restrict__ dst, int* __restrict__ bucket_cnt,
                            int nE) {
    __shared__ int h[128];
    int t = threadIdx.x;
    if (t < 128) h[t] = 0;
    __syncthreads();
    int i0 = blockIdx.x * CHUNK;
    int cn = min(CHUNK, nE - i0);
    for (int i = t; i < cn; i += 256) atomicAdd(&h[dst[i0 + i] >> BKT_SHIFT], 1);
    __syncthreads();
    if (t < 128 && h[t] > 0) atomicAdd(&bucket_cnt[t], h[t]);
}

// ---- scan the <=128 bucket counts -> base & cursor; row_ptr[n] = nE --------

__global__ void scan_buckets(const int* __restrict__ bucket_cnt, int* __restrict__ bucket_base,
                             int* __restrict__ bucket_cursor, int* __restrict__ row_ptr,
                             int B, int n) {
    __shared__ int s[128];
    int t = threadIdx.x;  // 128 threads
    int v = (t < B) ? bucket_cnt[t] : 0;
    s[t] = v;
    __syncthreads();
    for (int off = 1; off < 128; off <<= 1) {
        int u = (t >= off) ? s[t - off] : 0;
        __syncthreads();
        s[t] += u;
        __syncthreads();
    }
    if (t < B) {
        int excl = s[t] - v;
        bucket_base[t] = excl;
        bucket_cursor[t] = excl;
    }
    if (t == 127) {
        bucket_base[B] = s[127];   // == nE
        row_ptr[n] = s[127];
    }
}

// ---- level-1 partition: chunk -> in-LDS counting sort -> contiguous runs ---
// Packed word: (dst & (BKT_NODES-1)) << 17 | src     (src < 2^17)

__global__ void partition(const int* __restrict__ src, const int* __restrict__ dst,
                          int* __restrict__ bucket_cursor, int* __restrict__ packed,
                          int nE, int B) {
    __shared__ int hist[128];            // counts, then local cursor
    __shared__ int delta[128];           // global_base - local_excl
    __shared__ int sorted[CHUNK];
    __shared__ unsigned char sortedb[CHUNK];
    int t = threadIdx.x;  // 256 threads
    int i0 = blockIdx.x * CHUNK;
    int cn = min(CHUNK, nE - i0);

    if (t < 128) hist[t] = 0;
    __syncthreads();
    for (int i = t; i < cn; i += 256) atomicAdd(&hist[dst[i0 + i] >> BKT_SHIFT], 1);
    __syncthreads();

    __shared__ int s[128];
    int v = (t < 128) ? hist[t] : 0;
    if (t < 128) s[t] = v;
    __syncthreads();
    for (int off = 1; off < 128; off <<= 1) {
        int u = (t >= off && t < 128) ? s[t - off] : 0;
        __syncthreads();
        if (t < 128) s[t] += u;
        __syncthreads();
    }
    if (t < 128) {
        int excl = s[t] - v;
        int rb = 0;
        if (t < B && v > 0) rb = atomicAdd(&bucket_cursor[t], v);
        delta[t] = rb - excl;
        hist[t] = excl;   // local cursor for the LDS scatter
    }
    __syncthreads();

    for (int i = t; i < cn; i += 256) {
        int d = dst[i0 + i];
        int b = d >> BKT_SHIFT;
        int pp = atomicAdd(&hist[b], 1);
        sorted[pp]  = ((d & (BKT_NODES - 1)) << 17) | src[i0 + i];
        sortedb[pp] = (unsigned char)b;
    }
    __syncthreads();

    for (int i = t; i < cn; i += 256) {
        packed[delta[sortedb[i]] + i] = sorted[i];
    }
}

// ---- level-2: per-bucket CSR finalize (count, scan, scatter in one window) -

__global__ void bucket_csr(const int* __restrict__ packed, const int* __restrict__ bucket_base,
                           int* __restrict__ row_ptr, float* __restrict__ dinv,
                           int* __restrict__ adj, int n) {
    __shared__ int s[BKT_NODES];
    __shared__ int cur[BKT_NODES];
    int t = threadIdx.x;  // 1024 threads
    int b = blockIdx.x;
    int lo = bucket_base[b], hi = bucket_base[b + 1];

    s[t] = 0;
    __syncthreads();
    for (int i = lo + t; i < hi; i += BKT_NODES) atomicAdd(&s[packed[i] >> 17], 1);
    __syncthreads();

    int v = s[t];
    __syncthreads();
    for (int off = 1; off < BKT_NODES; off <<= 1) {
        int u = (t >= off) ? s[t - off] : 0;
        __syncthreads();
        s[t] += u;
        __syncthreads();
    }
    int gbeg = lo + s[t] - v;   // exclusive prefix + bucket base
    int node = (b << BKT_SHIFT) + t;
    if (node < n) {
        row_ptr[node] = gbeg;
        dinv[node] = rsqrtf(1.0f + (float)v);   // self-loop included
    }
    cur[t] = gbeg;
    __syncthreads();

    for (int i = lo + t; i < hi; i += BKT_NODES) {
        int w = packed[i];
        int pos = atomicAdd(&cur[w >> 17], 1);
        adj[pos] = w & 0x1FFFF;
    }
}

// ---- prescale: Xp = diag(dinv) * X  (float4 streaming) ---------------------

__global__ void prescale(const float* __restrict__ x, const float* __restrict__ dinv,
                         float* __restrict__ xp, int n) {
    int idx = blockIdx.x * blockDim.x + threadIdx.x;   // one float4 per thread
    if (idx < n * (D / 4)) {
        int row = idx >> 4;
        float di = dinv[row];
        float4 v = ((const float4*)x)[idx];
        v.x *= di; v.y *= di; v.z *= di; v.w *= di;
        ((float4*)xp)[idx] = v;
    }
}

// ---- pure gather-sum: S[i] = hp[i] + sum_{s in N(i)} hp[s] -----------------
// hp is PRE-SCALED (hp = dinv*h), so the self term carries NO extra dinv —
// the single outer dinv_i is applied in the GEMM epilogue.
// One node per 16-lane quarter (4 consecutive nodes per wave). Lane p of a
// quarter holds features [4p..4p+3] as float4. 16 edges per quarter per chunk,
// consumed as two bursts of 8 back-to-back row loads. Tail edges load row 0
// with multiplier 0.
__launch_bounds__(256, 4)
__global__ void agg(const float* __restrict__ hp, const int* __restrict__ row_ptr,
                    const int* __restrict__ adj, float* __restrict__ S, int n) {
    const int lane = threadIdx.x & 63;
    const int q = lane >> 4;   // quarter = which of the wave's 4 nodes
    const int p = lane & 15;   // feature group: features 4p..4p+3
    const int wave = (blockIdx.x * blockDim.x + threadIdx.x) >> 6;
    const int nw = (gridDim.x * blockDim.x) >> 6;

    for (int nb = wave * 4; nb < n; nb += nw * 4) {
        int nq = nb + q;
        bool valid = nq < n;
        int nqc = valid ? nq : 0;
        int rb = row_ptr[nqc];
        int re = row_ptr[nqc + 1];
        int len = valid ? (re - rb) : 0;

        // self-loop term: hp already prescaled -> no extra factor
        float4 acc = ((const float4*)(hp + (size_t)nqc * D))[p];

        int lm = len;
        lm = max(lm, __shfl_xor(lm, 16, 64));
        lm = max(lm, __shfl_xor(lm, 32, 64));

        for (int base = 0; base < lm; base += 16) {
            int rem = len - base;            // this quarter's remaining edges
            int idx_l = 0;
            if (p < rem) idx_l = adj[rb + base + p];
#pragma unroll
            for (int jj = 0; jj < 16; jj += 8) {
                int ss[8]; float4 vv[8];
#pragma unroll
                for (int u = 0; u < 8; ++u) {
                    ss[u] = __shfl(idx_l, (q << 4) | (jj + u), 64);
                }
#pragma unroll
                for (int u = 0; u < 8; ++u) {
                    vv[u] = ((const float4*)(hp + (size_t)ss[u] * D))[p];
                }
#pragma unroll
                for (int u = 0; u < 8; ++u) {
                    float m = (jj + u < rem) ? 1.0f : 0.0f;
                    acc.x = fmaf(m, vv[u].x, acc.x);
                    acc.y = fmaf(m, vv[u].y, acc.y);
                    acc.z = fmaf(m, vv[u].z, acc.z);
                    acc.w = fmaf(m, vv[u].w, acc.w);
                }
            }
        }
        if (valid) ((float4*)(S + (size_t)nq * D))[p] = acc;
    }
}

// ---- streaming 64x64 transform with folded scaling -------------------------
// Quarter-local shfl GEMM on coalesced rows of S.
// MODE 0: Hp = dinv * relu(dinv * (S@W1))        (pre-scaled layer-1 output)
// MODE 1: out = dinv * (S@W2) + bias             (final output)
template <int MODE>
__global__ void gemm64q(const float* __restrict__ S, const float* __restrict__ W,
                        const float* __restrict__ bias, const float* __restrict__ dinv,
                        float* __restrict__ out, int n) {
    __shared__ float Wl[D * D];
    for (int i = threadIdx.x; i < D * D; i += blockDim.x) Wl[i] = W[i];
    __syncthreads();

    const int lane = threadIdx.x & 63;
    const int q = lane >> 4;
    const int p = lane & 15;
    const int wave = (blockIdx.x * blockDim.x + threadIdx.x) >> 6;
    const int nw = (gridDim.x * blockDim.x) >> 6;

    const float4 bv = (MODE == 1) ? ((const float4*)bias)[p]
                                  : make_float4(0.f, 0.f, 0.f, 0.f);

    for (int nb = wave * 4; nb < n; nb += nw * 4) {
        int nq = nb + q;
        bool valid = nq < n;
        int nqc = valid ? nq : 0;
        float dn = valid ? dinv[nqc] : 0.0f;
        float4 acc = ((const float4*)(S + (size_t)nqc * D))[p];

        float4 y = make_float4(0.f, 0.f, 0.f, 0.f);
#pragma unroll
        for (int kp = 0; kp < 16; ++kp) {
            int sl = (q << 4) | kp;
            float s0 = __shfl(acc.x, sl, 64);
            float s1 = __shfl(acc.y, sl, 64);
            float s2 = __shfl(acc.z, sl, 64);
            float s3 = __shfl(acc.w, sl, 64);
            const float4 w0 = *(const float4*)&Wl[(4 * kp + 0) * D + 4 * p];
            const float4 w1 = *(const float4*)&Wl[(4 * kp + 1) * D + 4 * p];
            const float4 w2 = *(const float4*)&Wl[(4 * kp + 2) * D + 4 * p];
            const float4 w3 = *(const float4*)&Wl[(4 * kp + 3) * D + 4 * p];
            y.x = fmaf(s0, w0.x, fmaf(s1, w1.x, fmaf(s2, w2.x, fmaf(s3, w3.x, y.x))));
            y.y = fmaf(s0, w0.y, fmaf(s1, w1.y, fmaf(s2, w2.y, fmaf(s3, w3.y, y.y))));
            y.z = fmaf(s0, w0.z, fmaf(s1, w1.z, fmaf(s2, w2.z, fmaf(s3, w3.z, y.z))));
            y.w = fmaf(s0, w0.w, fmaf(s1, w1.w, fmaf(s2, w2.w, fmaf(s3, w3.w, y.w))));
        }

        float4 r;
        if (MODE == 0) {
            r.x = dn * fmaxf(dn * y.x, 0.f);
            r.y = dn * fmaxf(dn * y.y, 0.f);
            r.z = dn * fmaxf(dn * y.z, 0.f);
            r.w = dn * fmaxf(dn * y.w, 0.f);
        } else {
            r.x = fmaf(dn, y.x, bv.x);
            r.y = fmaf(dn, y.y, bv.y);
            r.z = fmaf(dn, y.z, bv.z);
            r.w = fmaf(dn, y.w, bv.w);
        }
        if (valid) ((float4*)(out + (size_t)nq * D))[p] = r;
    }
}

// ---- launch ----------------------------------------------------------------

extern "C" void kernel_launch(void* const* d_in, const int* in_sizes, int n_in,
                              void* d_out, int out_size, void* d_ws, size_t ws_size,
                              hipStream_t stream) {
    const float* x  = (const float*)d_in[0];
    const float* W1 = (const float*)d_in[1];
    const float* W2 = (const float*)d_in[2];
    const float* b2 = (const float*)d_in[3];
    const int*   ei = (const int*)d_in[4];

    int n  = in_sizes[0] / D;   // 100000
    int nE = in_sizes[4] / 2;   // 1600000
    const int* src = ei;        // message source
    const int* dst = ei + nE;   // aggregation target

    int B = (n + BKT_NODES - 1) >> BKT_SHIFT;  // 98 buckets (<=128 assumed)

    // workspace layout (aligned to 256B):
    //   row_ptr | dinv | bucket_cnt | bucket_base | bucket_cursor | adj |
    //   F0 [n*D] (aliases packed: packed dead before prescale writes F0) |
    //   S [n*D]
    auto align = [](size_t v) { return (v + 255) & ~(size_t)255; };
    char* ws = (char*)d_ws;
    size_t off = 0;
    int* row_ptr   = (int*)(ws + off);   off += align((size_t)(n + 1) * 4);
    float* dinv    = (float*)(ws + off); off += align((size_t)n * 4);
    int* bucket_cnt    = (int*)(ws + off); off += align(128 * 4);
    int* bucket_base   = (int*)(ws + off); off += align(129 * 4);
    int* bucket_cursor = (int*)(ws + off); off += align(128 * 4);
    int* adj       = (int*)(ws + off);   off += align((size_t)nE * 4);
    float* F0      = (float*)(ws + off); off += align((size_t)n * D * 4);
    float* Sbuf    = (float*)(ws + off);
    int* packed    = (int*)F0;           // alias: dead before F0 is written
    float* out = (float*)d_out;

    int nchunks = (nE + CHUNK - 1) / CHUNK;  // 196

    // CSR build (binned, write-locality preserving)
    zero_int<<<1, 128, 0, stream>>>(bucket_cnt, 128);
    bucket_hist<<<nchunks, 256, 0, stream>>>(dst, bucket_cnt, nE);
    scan_buckets<<<1, 128, 0, stream>>>(bucket_cnt, bucket_base, bucket_cursor, row_ptr, B, n);
    partition<<<nchunks, 256, 0, stream>>>(src, dst, bucket_cursor, packed, nE, B);
    bucket_csr<<<B, BKT_NODES, 0, stream>>>(packed, bucket_base, row_ptr, dinv, adj, n);

    // prescale: F0 = diag(dinv) * x
    int nq4 = n * (D / 4);
    prescale<<<(nq4 + 255) / 256, 256, 0, stream>>>(x, dinv, F0, n);

    // layer 1: S = gather(F0) ; F0 = dinv*relu(dinv*(S@W1))   (F0 reused as Hp)
    agg<<<2048, 256, 0, stream>>>(F0, row_ptr, adj, Sbuf, n);
    gemm64q<0><<<2048, 256, 0, stream>>>(Sbuf, W1, nullptr, dinv, F0, n);

    // layer 2: S = gather(F0) ; out = dinv*(S@W2) + b2
    agg<<<2048, 256, 0, stream>>>(F0, row_ptr, adj, Sbuf, n);
    gemm64q<1><<<2048, 256, 0, stream>>>(Sbuf, W2, b2, dinv, out, n);
}

// Round 10
// 308.033 us; speedup vs baseline: 1.1815x; 1.1815x over previous
//
#include <hip/hip_runtime.h>

#define D 64
#define CHUNK 8192          // edges per partition block
#define BKT_SHIFT 10        // 1024 nodes per bucket
#define BKT_NODES 1024
#define GROWS 64            // rows per gemm block-tile
#define SSTR 68             // padded LDS row stride for S tile

// ---- misc ------------------------------------------------------------------

__global__ void zero_int(int* __restrict__ p, int n) {
    int i = blockIdx.x * blockDim.x + threadIdx.x;
    if (i < n) p[i] = 0;
}

// ---- level-1: bucket histogram of dst>>BKT_SHIFT ---------------------------

__global__ void bucket_hist(const int* __restrict__ dst, int* __restrict__ bucket_cnt,
                            int nE) {
    __shared__ int h[128];
    int t = threadIdx.x;
    if (t < 128) h[t] = 0;
    __syncthreads();
    int i0 = blockIdx.x * CHUNK;
    int cn = min(CHUNK, nE - i0);
    for (int i = t; i < cn; i += 256) atomicAdd(&h[dst[i0 + i] >> BKT_SHIFT], 1);
    __syncthreads();
    if (t < 128 && h[t] > 0) atomicAdd(&bucket_cnt[t], h[t]);
}

// ---- scan the <=128 bucket counts -> base & cursor; row_ptr[n] = nE --------

__global__ void scan_buckets(const int* __restrict__ bucket_cnt, int* __restrict__ bucket_base,
                             int* __restrict__ bucket_cursor, int* __restrict__ row_ptr,
                             int B, int n) {
    __shared__ int s[128];
    int t = threadIdx.x;  // 128 threads
    int v = (t < B) ? bucket_cnt[t] : 0;
    s[t] = v;
    __syncthreads();
    for (int off = 1; off < 128; off <<= 1) {
        int u = (t >= off) ? s[t - off] : 0;
        __syncthreads();
        s[t] += u;
        __syncthreads();
    }
    if (t < B) {
        int excl = s[t] - v;
        bucket_base[t] = excl;
        bucket_cursor[t] = excl;
    }
    if (t == 127) {
        bucket_base[B] = s[127];   // == nE
        row_ptr[n] = s[127];
    }
}

// ---- level-1 partition: chunk -> in-LDS counting sort -> contiguous runs ---
// Packed word: (dst & (BKT_NODES-1)) << 17 | src     (src < 2^17)

__global__ void partition(const int* __restrict__ src, const int* __restrict__ dst,
                          int* __restrict__ bucket_cursor, int* __restrict__ packed,
                          int nE, int B) {
    __shared__ int hist[128];            // counts, then local cursor
    __shared__ int delta[128];           // global_base - local_excl
    __shared__ int sorted[CHUNK];
    __shared__ unsigned char sortedb[CHUNK];
    int t = threadIdx.x;  // 256 threads
    int i0 = blockIdx.x * CHUNK;
    int cn = min(CHUNK, nE - i0);

    if (t < 128) hist[t] = 0;
    __syncthreads();
    for (int i = t; i < cn; i += 256) atomicAdd(&hist[dst[i0 + i] >> BKT_SHIFT], 1);
    __syncthreads();

    __shared__ int s[128];
    int v = (t < 128) ? hist[t] : 0;
    if (t < 128) s[t] = v;
    __syncthreads();
    for (int off = 1; off < 128; off <<= 1) {
        int u = (t >= off && t < 128) ? s[t - off] : 0;
        __syncthreads();
        if (t < 128) s[t] += u;
        __syncthreads();
    }
    if (t < 128) {
        int excl = s[t] - v;
        int rb = 0;
        if (t < B && v > 0) rb = atomicAdd(&bucket_cursor[t], v);
        delta[t] = rb - excl;
        hist[t] = excl;   // local cursor for the LDS scatter
    }
    __syncthreads();

    for (int i = t; i < cn; i += 256) {
        int d = dst[i0 + i];
        int b = d >> BKT_SHIFT;
        int pp = atomicAdd(&hist[b], 1);
        sorted[pp]  = ((d & (BKT_NODES - 1)) << 17) | src[i0 + i];
        sortedb[pp] = (unsigned char)b;
    }
    __syncthreads();

    for (int i = t; i < cn; i += 256) {
        packed[delta[sortedb[i]] + i] = sorted[i];
    }
}

// ---- level-2: per-bucket CSR finalize (count, scan, scatter in one window) -

__global__ void bucket_csr(const int* __restrict__ packed, const int* __restrict__ bucket_base,
                           int* __restrict__ row_ptr, float* __restrict__ dinv,
                           int* __restrict__ adj, int n) {
    __shared__ int s[BKT_NODES];
    __shared__ int cur[BKT_NODES];
    int t = threadIdx.x;  // 1024 threads
    int b = blockIdx.x;
    int lo = bucket_base[b], hi = bucket_base[b + 1];

    s[t] = 0;
    __syncthreads();
    for (int i = lo + t; i < hi; i += BKT_NODES) atomicAdd(&s[packed[i] >> 17], 1);
    __syncthreads();

    int v = s[t];
    __syncthreads();
    for (int off = 1; off < BKT_NODES; off <<= 1) {
        int u = (t >= off) ? s[t - off] : 0;
        __syncthreads();
        s[t] += u;
        __syncthreads();
    }
    int gbeg = lo + s[t] - v;   // exclusive prefix + bucket base
    int node = (b << BKT_SHIFT) + t;
    if (node < n) {
        row_ptr[node] = gbeg;
        dinv[node] = rsqrtf(1.0f + (float)v);   // self-loop included
    }
    cur[t] = gbeg;
    __syncthreads();

    for (int i = lo + t; i < hi; i += BKT_NODES) {
        int w = packed[i];
        int pos = atomicAdd(&cur[w >> 17], 1);
        adj[pos] = w & 0x1FFFF;
    }
}

// ---- prescale: Xp = diag(dinv) * X  (float4 streaming) ---------------------

__global__ void prescale(const float* __restrict__ x, const float* __restrict__ dinv,
                         float* __restrict__ xp, int n) {
    int idx = blockIdx.x * blockDim.x + threadIdx.x;   // one float4 per thread
    if (idx < n * (D / 4)) {
        int row = idx >> 4;
        float di = dinv[row];
        float4 v = ((const float4*)x)[idx];
        v.x *= di; v.y *= di; v.z *= di; v.w *= di;
        ((float4*)xp)[idx] = v;
    }
}

// ---- pure gather-sum: S[i] = hp[i] + sum_{s in N(i)} hp[s] -----------------
// hp is PRE-SCALED (hp = dinv*h); outer dinv_i applied in the GEMM epilogue.
__launch_bounds__(256, 4)
__global__ void agg(const float* __restrict__ hp, const int* __restrict__ row_ptr,
                    const int* __restrict__ adj, float* __restrict__ S, int n) {
    const int lane = threadIdx.x & 63;
    const int q = lane >> 4;   // quarter = which of the wave's 4 nodes
    const int p = lane & 15;   // feature group: features 4p..4p+3
    const int wave = (blockIdx.x * blockDim.x + threadIdx.x) >> 6;
    const int nw = (gridDim.x * blockDim.x) >> 6;

    for (int nb = wave * 4; nb < n; nb += nw * 4) {
        int nq = nb + q;
        bool valid = nq < n;
        int nqc = valid ? nq : 0;
        int rb = row_ptr[nqc];
        int re = row_ptr[nqc + 1];
        int len = valid ? (re - rb) : 0;

        float4 acc = ((const float4*)(hp + (size_t)nqc * D))[p];

        int lm = len;
        lm = max(lm, __shfl_xor(lm, 16, 64));
        lm = max(lm, __shfl_xor(lm, 32, 64));

        for (int base = 0; base < lm; base += 16) {
            int rem = len - base;
            int idx_l = 0;
            if (p < rem) idx_l = adj[rb + base + p];
#pragma unroll
            for (int jj = 0; jj < 16; jj += 8) {
                int ss[8]; float4 vv[8];
#pragma unroll
                for (int u = 0; u < 8; ++u) {
                    ss[u] = __shfl(idx_l, (q << 4) | (jj + u), 64);
                }
#pragma unroll
                for (int u = 0; u < 8; ++u) {
                    vv[u] = ((const float4*)(hp + (size_t)ss[u] * D))[p];
                }
#pragma unroll
                for (int u = 0; u < 8; ++u) {
                    float m = (jj + u < rem) ? 1.0f : 0.0f;
                    acc.x = fmaf(m, vv[u].x, acc.x);
                    acc.y = fmaf(m, vv[u].y, acc.y);
                    acc.z = fmaf(m, vv[u].z, acc.z);
                    acc.w = fmaf(m, vv[u].w, acc.w);
                }
            }
        }
        if (valid) ((float4*)(S + (size_t)nq * D))[p] = acc;
    }
}

// ---- register-blocked tiled GEMM: out-tile = epi(dinv ⊙ (S_tile @ W)) ------
// One block = 64 rows x 64 cols. W (16 KB) + padded S tile (17 KB) in LDS.
// Thread (rg = t>>4, cg = t&15) computes rows 4rg..4rg+3 x cols 4cg..4cg+3.
// Per k-group of 4: 8 ds_read_b128 + 64 fma -> VALU-bound, no shfl/bpermute.
// MODE 0: out = dinv * relu(dinv * y)        (pre-scaled layer-1 output)
// MODE 1: out = dinv * y + bias              (final output)
template <int MODE>
__launch_bounds__(256, 4)
__global__ void tgemm(const float* __restrict__ S, const float* __restrict__ W,
                      const float* __restrict__ bias, const float* __restrict__ dinv,
                      float* __restrict__ out, int n) {
    __shared__ float Wl[D * D];          // stride 64
    __shared__ float Sl[GROWS * SSTR];   // stride 68 (pad kills pow2 conflicts)
    const int t = threadIdx.x;

    // stage W: 1024 float4, coalesced
    for (int i = t; i < D * D / 4; i += 256)
        ((float4*)Wl)[i] = ((const float4*)W)[i];

    // stage S tile: 64 rows x 16 float4, coalesced; OOB rows -> 0
    const int R0 = blockIdx.x * GROWS;
    for (int i = t; i < GROWS * 16; i += 256) {
        int row = i >> 4, kq = i & 15;
        float4 v = make_float4(0.f, 0.f, 0.f, 0.f);
        if (R0 + row < n) v = ((const float4*)(S + (size_t)(R0 + row) * D))[kq];
        *(float4*)&Sl[row * SSTR + kq * 4] = v;
    }
    __syncthreads();

    const int cg = t & 15;   // cols 4cg..4cg+3
    const int rg = t >> 4;   // rows 4rg..4rg+3

    float4 acc0 = make_float4(0.f, 0.f, 0.f, 0.f);
    float4 acc1 = make_float4(0.f, 0.f, 0.f, 0.f);
    float4 acc2 = make_float4(0.f, 0.f, 0.f, 0.f);
    float4 acc3 = make_float4(0.f, 0.f, 0.f, 0.f);

#pragma unroll 4
    for (int k = 0; k < D; k += 4) {
        float4 a0 = *(const float4*)&Sl[(4 * rg + 0) * SSTR + k];
        float4 a1 = *(const float4*)&Sl[(4 * rg + 1) * SSTR + k];
        float4 a2 = *(const float4*)&Sl[(4 * rg + 2) * SSTR + k];
        float4 a3 = *(const float4*)&Sl[(4 * rg + 3) * SSTR + k];
        float4 w0 = *(const float4*)&Wl[(k + 0) * D + 4 * cg];
        float4 w1 = *(const float4*)&Wl[(k + 1) * D + 4 * cg];
        float4 w2 = *(const float4*)&Wl[(k + 2) * D + 4 * cg];
        float4 w3 = *(const float4*)&Wl[(k + 3) * D + 4 * cg];
#define MAC(ACC, A)                                                        \
        ACC.x = fmaf(A.x, w0.x, fmaf(A.y, w1.x, fmaf(A.z, w2.x, fmaf(A.w, w3.x, ACC.x)))); \
        ACC.y = fmaf(A.x, w0.y, fmaf(A.y, w1.y, fmaf(A.z, w2.y, fmaf(A.w, w3.y, ACC.y)))); \
        ACC.z = fmaf(A.x, w0.z, fmaf(A.y, w1.z, fmaf(A.z, w2.z, fmaf(A.w, w3.z, ACC.z)))); \
        ACC.w = fmaf(A.x, w0.w, fmaf(A.y, w1.w, fmaf(A.z, w2.w, fmaf(A.w, w3.w, ACC.w))))
        MAC(acc0, a0);
        MAC(acc1, a1);
        MAC(acc2, a2);
        MAC(acc3, a3);
#undef MAC
    }

    const float4 bv = (MODE == 1) ? ((const float4*)bias)[cg]
                                  : make_float4(0.f, 0.f, 0.f, 0.f);
    float4 accs[4] = {acc0, acc1, acc2, acc3};
#pragma unroll
    for (int r = 0; r < 4; ++r) {
        int row = R0 + 4 * rg + r;
        if (row >= n) break;
        float dn = dinv[row];
        float4 y = accs[r];
        float4 o;
        if (MODE == 0) {
            o.x = dn * fmaxf(dn * y.x, 0.f);
            o.y = dn * fmaxf(dn * y.y, 0.f);
            o.z = dn * fmaxf(dn * y.z, 0.f);
            o.w = dn * fmaxf(dn * y.w, 0.f);
        } else {
            o.x = fmaf(dn, y.x, bv.x);
            o.y = fmaf(dn, y.y, bv.y);
            o.z = fmaf(dn, y.z, bv.z);
            o.w = fmaf(dn, y.w, bv.w);
        }
        ((float4*)(out + (size_t)row * D))[cg] = o;
    }
}

// ---- launch ----------------------------------------------------------------

extern "C" void kernel_launch(void* const* d_in, const int* in_sizes, int n_in,
                              void* d_out, int out_size, void* d_ws, size_t ws_size,
                              hipStream_t stream) {
    const float* x  = (const float*)d_in[0];
    const float* W1 = (const float*)d_in[1];
    const float* W2 = (const float*)d_in[2];
    const float* b2 = (const float*)d_in[3];
    const int*   ei = (const int*)d_in[4];

    int n  = in_sizes[0] / D;   // 100000
    int nE = in_sizes[4] / 2;   // 1600000
    const int* src = ei;        // message source
    const int* dst = ei + nE;   // aggregation target

    int B = (n + BKT_NODES - 1) >> BKT_SHIFT;  // 98 buckets (<=128 assumed)

    // workspace layout (aligned to 256B):
    //   row_ptr | dinv | bucket_cnt | bucket_base | bucket_cursor | adj |
    //   F0 [n*D] (aliases packed: packed dead before prescale writes F0) |
    //   S [n*D]
    auto align = [](size_t v) { return (v + 255) & ~(size_t)255; };
    char* ws = (char*)d_ws;
    size_t off = 0;
    int* row_ptr   = (int*)(ws + off);   off += align((size_t)(n + 1) * 4);
    float* dinv    = (float*)(ws + off); off += align((size_t)n * 4);
    int* bucket_cnt    = (int*)(ws + off); off += align(128 * 4);
    int* bucket_base   = (int*)(ws + off); off += align(129 * 4);
    int* bucket_cursor = (int*)(ws + off); off += align(128 * 4);
    int* adj       = (int*)(ws + off);   off += align((size_t)nE * 4);
    float* F0      = (float*)(ws + off); off += align((size_t)n * D * 4);
    float* Sbuf    = (float*)(ws + off);
    int* packed    = (int*)F0;           // alias: dead before F0 is written
    float* out = (float*)d_out;

    int nchunks = (nE + CHUNK - 1) / CHUNK;  // 196

    // CSR build (binned, write-locality preserving)
    zero_int<<<1, 128, 0, stream>>>(bucket_cnt, 128);
    bucket_hist<<<nchunks, 256, 0, stream>>>(dst, bucket_cnt, nE);
    scan_buckets<<<1, 128, 0, stream>>>(bucket_cnt, bucket_base, bucket_cursor, row_ptr, B, n);
    partition<<<nchunks, 256, 0, stream>>>(src, dst, bucket_cursor, packed, nE, B);
    bucket_csr<<<B, BKT_NODES, 0, stream>>>(packed, bucket_base, row_ptr, dinv, adj, n);

    // prescale: F0 = diag(dinv) * x
    int nq4 = n * (D / 4);
    prescale<<<(nq4 + 255) / 256, 256, 0, stream>>>(x, dinv, F0, n);

    int gblocks = (n + GROWS - 1) / GROWS;  // 1563

    // layer 1: S = gather(F0) ; F0 = dinv*relu(dinv*(S@W1))   (F0 reused as Hp)
    agg<<<2048, 256, 0, stream>>>(F0, row_ptr, adj, Sbuf, n);
    tgemm<0><<<gblocks, 256, 0, stream>>>(Sbuf, W1, nullptr, dinv, F0, n);

    // layer 2: S = gather(F0) ; out = dinv*(S@W2) + b2
    agg<<<2048, 256, 0, stream>>>(F0, row_ptr, adj, Sbuf, n);
    tgemm<1><<<gblocks, 256, 0, stream>>>(Sbuf, W2, b2, dinv, out, n);
}

// Round 11
// 300.588 us; speedup vs baseline: 1.2107x; 1.0248x over previous
//
#include <hip/hip_runtime.h>

#define D 64
#define CHUNK 8192          // edges per partition block
#define BKT_SHIFT 8         // 256 nodes per bucket
#define BKT_NODES 256
#define MAXB 512            // bucket-array sizing (B = 391 <= 512)
#define GROWS 64            // rows per gemm block-tile
#define SSTR 68             // padded LDS row stride for S tile

// ---- misc ------------------------------------------------------------------

__global__ void zero_int(int* __restrict__ p, int n) {
    int i = blockIdx.x * blockDim.x + threadIdx.x;
    if (i < n) p[i] = 0;
}

// ---- level-1: bucket histogram of dst>>BKT_SHIFT ---------------------------

__global__ void bucket_hist(const int* __restrict__ dst, int* __restrict__ bucket_cnt,
                            int nE) {
    __shared__ int h[MAXB];
    int t = threadIdx.x;  // 256 threads
    h[t] = 0; h[t + 256] = 0;
    __syncthreads();
    int i0 = blockIdx.x * CHUNK;
    int cn = min(CHUNK, nE - i0);
    for (int i = t; i < cn; i += 256) atomicAdd(&h[dst[i0 + i] >> BKT_SHIFT], 1);
    __syncthreads();
    if (h[t] > 0) atomicAdd(&bucket_cnt[t], h[t]);
    if (h[t + 256] > 0) atomicAdd(&bucket_cnt[t + 256], h[t + 256]);
}

// ---- scan the <=MAXB bucket counts -> base & cursor; row_ptr[n] = nE -------

__global__ void scan_buckets(const int* __restrict__ bucket_cnt, int* __restrict__ bucket_base,
                             int* __restrict__ bucket_cursor, int* __restrict__ row_ptr,
                             int B, int n) {
    __shared__ int s[MAXB];
    int t = threadIdx.x;  // 512 threads
    int v = (t < B) ? bucket_cnt[t] : 0;
    s[t] = v;
    __syncthreads();
    for (int off = 1; off < MAXB; off <<= 1) {
        int u = (t >= off) ? s[t - off] : 0;
        __syncthreads();
        s[t] += u;
        __syncthreads();
    }
    if (t < B) {
        int excl = s[t] - v;
        bucket_base[t] = excl;
        bucket_cursor[t] = excl;
    }
    if (t == MAXB - 1) {
        bucket_base[B] = s[t];   // == nE
        row_ptr[n] = s[t];
    }
}

// ---- level-1 partition: chunk -> in-LDS counting sort -> contiguous runs ---
// Packed word: (dst & (BKT_NODES-1)) << 17 | src     (src < 2^17)

__global__ void partition(const int* __restrict__ src, const int* __restrict__ dst,
                          int* __restrict__ bucket_cursor, int* __restrict__ packed,
                          int nE, int B) {
    __shared__ int hist[MAXB];           // counts, then local cursor
    __shared__ int delta[MAXB];          // global_base - local_excl
    __shared__ int s[MAXB];
    __shared__ int dstb[CHUNK];          // dst chunk buffer (avoid re-read)
    __shared__ int sorted[CHUNK];
    __shared__ unsigned short sortedb[CHUNK];
    int t = threadIdx.x;  // 512 threads
    int i0 = blockIdx.x * CHUNK;
    int cn = min(CHUNK, nE - i0);

    hist[t] = 0;
    __syncthreads();
    for (int i = t; i < cn; i += 512) {
        int d = dst[i0 + i];
        dstb[i] = d;
        atomicAdd(&hist[d >> BKT_SHIFT], 1);
    }
    __syncthreads();

    int v = hist[t];
    s[t] = v;
    __syncthreads();
    for (int off = 1; off < MAXB; off <<= 1) {
        int u = (t >= off) ? s[t - off] : 0;
        __syncthreads();
        s[t] += u;
        __syncthreads();
    }
    {
        int excl = s[t] - v;
        int rb = 0;
        if (t < B && v > 0) rb = atomicAdd(&bucket_cursor[t], v);
        delta[t] = rb - excl;
        hist[t] = excl;   // local cursor for the LDS scatter
    }
    __syncthreads();

    for (int i = t; i < cn; i += 512) {
        int d = dstb[i];
        int b = d >> BKT_SHIFT;
        int pp = atomicAdd(&hist[b], 1);
        sorted[pp]  = ((d & (BKT_NODES - 1)) << 17) | src[i0 + i];
        sortedb[pp] = (unsigned short)b;
    }
    __syncthreads();

    for (int i = t; i < cn; i += 512) {
        packed[delta[sortedb[i]] + i] = sorted[i];
    }
}

// ---- level-2: per-bucket CSR finalize + fused prescale ---------------------
// One block per 256-node bucket: count -> scan -> row_ptr/dinv -> adj scatter
// (16 KB window), then stream F0 = dinv * x for the bucket's rows (coalesced).

__global__ void bucket_csr(const int* __restrict__ packed, const int* __restrict__ bucket_base,
                           int* __restrict__ row_ptr, float* __restrict__ dinv,
                           int* __restrict__ adj, const float* __restrict__ x,
                           float* __restrict__ xp, int n) {
    __shared__ int s[BKT_NODES];
    __shared__ int cur[BKT_NODES];
    __shared__ float dv[BKT_NODES];
    int t = threadIdx.x;  // 256 threads
    int b = blockIdx.x;
    int lo = bucket_base[b], hi = bucket_base[b + 1];

    s[t] = 0;
    __syncthreads();
    for (int i = lo + t; i < hi; i += BKT_NODES) atomicAdd(&s[packed[i] >> 17], 1);
    __syncthreads();

    int v = s[t];
    __syncthreads();
    for (int off = 1; off < BKT_NODES; off <<= 1) {
        int u = (t >= off) ? s[t - off] : 0;
        __syncthreads();
        s[t] += u;
        __syncthreads();
    }
    int gbeg = lo + s[t] - v;   // exclusive prefix + bucket base
    int node = (b << BKT_SHIFT) + t;
    float di = rsqrtf(1.0f + (float)v);   // self-loop included
    if (node < n) {
        row_ptr[node] = gbeg;
        dinv[node] = di;
    }
    dv[t] = di;
    cur[t] = gbeg;
    __syncthreads();

    for (int i = lo + t; i < hi; i += BKT_NODES) {
        int w = packed[i];
        int pos = atomicAdd(&cur[w >> 17], 1);
        adj[pos] = w & 0x1FFFF;
    }

    // fused prescale for this bucket's 256 rows: F0 = dinv * x  (coalesced)
    int base = b << BKT_SHIFT;
    for (int i = t; i < BKT_NODES * (D / 4); i += BKT_NODES) {
        int row = i >> 4, kq = i & 15;
        int nd = base + row;
        if (nd < n) {
            float4 vv = ((const float4*)(x + (size_t)nd * D))[kq];
            float d2 = dv[row];
            vv.x *= d2; vv.y *= d2; vv.z *= d2; vv.w *= d2;
            ((float4*)(xp + (size_t)nd * D))[kq] = vv;
        }
    }
}

// ---- pure gather-sum: S[i] = hp[i] + sum_{s in N(i)} hp[s] -----------------
// hp is PRE-SCALED (hp = dinv*h); outer dinv_i applied in the GEMM epilogue.
__launch_bounds__(256, 4)
__global__ void agg(const float* __restrict__ hp, const int* __restrict__ row_ptr,
                    const int* __restrict__ adj, float* __restrict__ S, int n) {
    const int lane = threadIdx.x & 63;
    const int q = lane >> 4;   // quarter = which of the wave's 4 nodes
    const int p = lane & 15;   // feature group: features 4p..4p+3
    const int wave = (blockIdx.x * blockDim.x + threadIdx.x) >> 6;
    const int nw = (gridDim.x * blockDim.x) >> 6;

    for (int nb = wave * 4; nb < n; nb += nw * 4) {
        int nq = nb + q;
        bool valid = nq < n;
        int nqc = valid ? nq : 0;
        int rb = row_ptr[nqc];
        int re = row_ptr[nqc + 1];
        int len = valid ? (re - rb) : 0;

        float4 acc = ((const float4*)(hp + (size_t)nqc * D))[p];

        int lm = len;
        lm = max(lm, __shfl_xor(lm, 16, 64));
        lm = max(lm, __shfl_xor(lm, 32, 64));

        for (int base = 0; base < lm; base += 16) {
            int rem = len - base;
            int idx_l = 0;
            if (p < rem) idx_l = adj[rb + base + p];
#pragma unroll
            for (int jj = 0; jj < 16; jj += 8) {
                int ss[8]; float4 vv[8];
#pragma unroll
                for (int u = 0; u < 8; ++u) {
                    ss[u] = __shfl(idx_l, (q << 4) | (jj + u), 64);
                }
#pragma unroll
                for (int u = 0; u < 8; ++u) {
                    vv[u] = ((const float4*)(hp + (size_t)ss[u] * D))[p];
                }
#pragma unroll
                for (int u = 0; u < 8; ++u) {
                    float m = (jj + u < rem) ? 1.0f : 0.0f;
                    acc.x = fmaf(m, vv[u].x, acc.x);
                    acc.y = fmaf(m, vv[u].y, acc.y);
                    acc.z = fmaf(m, vv[u].z, acc.z);
                    acc.w = fmaf(m, vv[u].w, acc.w);
                }
            }
        }
        if (valid) ((float4*)(S + (size_t)nq * D))[p] = acc;
    }
}

// ---- register-blocked tiled GEMM: out-tile = epi(dinv ⊙ (S_tile @ W)) ------
// MODE 0: out = dinv * relu(dinv * y)        (pre-scaled layer-1 output)
// MODE 1: out = dinv * y + bias              (final output)
template <int MODE>
__launch_bounds__(256, 4)
__global__ void tgemm(const float* __restrict__ S, const float* __restrict__ W,
                      const float* __restrict__ bias, const float* __restrict__ dinv,
                      float* __restrict__ out, int n) {
    __shared__ float Wl[D * D];          // stride 64
    __shared__ float Sl[GROWS * SSTR];   // stride 68 (pad kills pow2 conflicts)
    const int t = threadIdx.x;

    for (int i = t; i < D * D / 4; i += 256)
        ((float4*)Wl)[i] = ((const float4*)W)[i];

    const int R0 = blockIdx.x * GROWS;
    for (int i = t; i < GROWS * 16; i += 256) {
        int row = i >> 4, kq = i & 15;
        float4 v = make_float4(0.f, 0.f, 0.f, 0.f);
        if (R0 + row < n) v = ((const float4*)(S + (size_t)(R0 + row) * D))[kq];
        *(float4*)&Sl[row * SSTR + kq * 4] = v;
    }
    __syncthreads();

    const int cg = t & 15;   // cols 4cg..4cg+3
    const int rg = t >> 4;   // rows 4rg..4rg+3

    float4 acc0 = make_float4(0.f, 0.f, 0.f, 0.f);
    float4 acc1 = make_float4(0.f, 0.f, 0.f, 0.f);
    float4 acc2 = make_float4(0.f, 0.f, 0.f, 0.f);
    float4 acc3 = make_float4(0.f, 0.f, 0.f, 0.f);

#pragma unroll 4
    for (int k = 0; k < D; k += 4) {
        float4 a0 = *(const float4*)&Sl[(4 * rg + 0) * SSTR + k];
        float4 a1 = *(const float4*)&Sl[(4 * rg + 1) * SSTR + k];
        float4 a2 = *(const float4*)&Sl[(4 * rg + 2) * SSTR + k];
        float4 a3 = *(const float4*)&Sl[(4 * rg + 3) * SSTR + k];
        float4 w0 = *(const float4*)&Wl[(k + 0) * D + 4 * cg];
        float4 w1 = *(const float4*)&Wl[(k + 1) * D + 4 * cg];
        float4 w2 = *(const float4*)&Wl[(k + 2) * D + 4 * cg];
        float4 w3 = *(const float4*)&Wl[(k + 3) * D + 4 * cg];
#define MAC(ACC, A)                                                        \
        ACC.x = fmaf(A.x, w0.x, fmaf(A.y, w1.x, fmaf(A.z, w2.x, fmaf(A.w, w3.x, ACC.x)))); \
        ACC.y = fmaf(A.x, w0.y, fmaf(A.y, w1.y, fmaf(A.z, w2.y, fmaf(A.w, w3.y, ACC.y)))); \
        ACC.z = fmaf(A.x, w0.z, fmaf(A.y, w1.z, fmaf(A.z, w2.z, fmaf(A.w, w3.z, ACC.z)))); \
        ACC.w = fmaf(A.x, w0.w, fmaf(A.y, w1.w, fmaf(A.z, w2.w, fmaf(A.w, w3.w, ACC.w))))
        MAC(acc0, a0);
        MAC(acc1, a1);
        MAC(acc2, a2);
        MAC(acc3, a3);
#undef MAC
    }

    const float4 bv = (MODE == 1) ? ((const float4*)bias)[cg]
                                  : make_float4(0.f, 0.f, 0.f, 0.f);
    float4 accs[4] = {acc0, acc1, acc2, acc3};
#pragma unroll
    for (int r = 0; r < 4; ++r) {
        int row = R0 + 4 * rg + r;
        if (row >= n) break;
        float dn = dinv[row];
        float4 y = accs[r];
        float4 o;
        if (MODE == 0) {
            o.x = dn * fmaxf(dn * y.x, 0.f);
            o.y = dn * fmaxf(dn * y.y, 0.f);
            o.z = dn * fmaxf(dn * y.z, 0.f);
            o.w = dn * fmaxf(dn * y.w, 0.f);
        } else {
            o.x = fmaf(dn, y.x, bv.x);
            o.y = fmaf(dn, y.y, bv.y);
            o.z = fmaf(dn, y.z, bv.z);
            o.w = fmaf(dn, y.w, bv.w);
        }
        ((float4*)(out + (size_t)row * D))[cg] = o;
    }
}

// ---- launch ----------------------------------------------------------------

extern "C" void kernel_launch(void* const* d_in, const int* in_sizes, int n_in,
                              void* d_out, int out_size, void* d_ws, size_t ws_size,
                              hipStream_t stream) {
    const float* x  = (const float*)d_in[0];
    const float* W1 = (const float*)d_in[1];
    const float* W2 = (const float*)d_in[2];
    const float* b2 = (const float*)d_in[3];
    const int*   ei = (const int*)d_in[4];

    int n  = in_sizes[0] / D;   // 100000
    int nE = in_sizes[4] / 2;   // 1600000
    const int* src = ei;        // message source
    const int* dst = ei + nE;   // aggregation target

    int B = (n + BKT_NODES - 1) >> BKT_SHIFT;  // 391 buckets (<= MAXB)

    // workspace layout (aligned to 256B):
    //   row_ptr | dinv | bucket_cnt | bucket_base | bucket_cursor | adj |
    //   F0 [n*D] (aliases packed: packed dead after bucket_csr reads it,
    //             and bucket_csr writes F0 only after its packed reads) |
    //   S [n*D]
    auto align = [](size_t v) { return (v + 255) & ~(size_t)255; };
    char* ws = (char*)d_ws;
    size_t off = 0;
    int* row_ptr   = (int*)(ws + off);   off += align((size_t)(n + 1) * 4);
    float* dinv    = (float*)(ws + off); off += align((size_t)n * 4);
    int* bucket_cnt    = (int*)(ws + off); off += align(MAXB * 4);
    int* bucket_base   = (int*)(ws + off); off += align((MAXB + 1) * 4);
    int* bucket_cursor = (int*)(ws + off); off += align(MAXB * 4);
    int* adj       = (int*)(ws + off);   off += align((size_t)nE * 4);
    int* packed    = (int*)(ws + off);   off += align((size_t)nE * 4);
    float* F0      = (float*)(ws + off); off += align((size_t)n * D * 4);
    float* Sbuf    = (float*)(ws + off);
    float* out = (float*)d_out;

    int nchunks = (nE + CHUNK - 1) / CHUNK;  // 196

    // CSR build (binned, write-locality preserving) + fused prescale
    zero_int<<<2, 256, 0, stream>>>(bucket_cnt, MAXB);
    bucket_hist<<<nchunks, 256, 0, stream>>>(dst, bucket_cnt, nE);
    scan_buckets<<<1, MAXB, 0, stream>>>(bucket_cnt, bucket_base, bucket_cursor, row_ptr, B, n);
    partition<<<nchunks, 512, 0, stream>>>(src, dst, bucket_cursor, packed, nE, B);
    bucket_csr<<<B, BKT_NODES, 0, stream>>>(packed, bucket_base, row_ptr, dinv, adj, x, F0, n);

    int gblocks = (n + GROWS - 1) / GROWS;  // 1563

    // layer 1: S = gather(F0) ; F0 = dinv*relu(dinv*(S@W1))   (F0 reused as Hp)
    agg<<<2048, 256, 0, stream>>>(F0, row_ptr, adj, Sbuf, n);
    tgemm<0><<<gblocks, 256, 0, stream>>>(Sbuf, W1, nullptr, dinv, F0, n);

    // layer 2: S = gather(F0) ; out = dinv*(S@W2) + b2
    agg<<<2048, 256, 0, stream>>>(F0, row_ptr, adj, Sbuf, n);
    tgemm<1><<<gblocks, 256, 0, stream>>>(Sbuf, W2, b2, dinv, out, n);
}

// Round 12
// 235.370 us; speedup vs baseline: 1.5462x; 1.2771x over previous
//
#include <hip/hip_runtime.h>

#define D 64
#define CHUNK 8192          // edges per partition block
#define BKT_SHIFT 8         // 256 nodes per bucket
#define BKT_NODES 256
#define MAXB 512            // bucket-array sizing (B = 391 <= 512)
#define GROWS 64            // rows per gemm block-tile
#define SSTR 68             // padded LDS row stride for S tile

typedef unsigned int u32;

// bf16 helpers: storage as u32 pairs (lo = even feature, hi = odd feature)
__device__ __forceinline__ u32 bfr(float v) {          // fp32 -> bf16 bits (RNE)
    u32 x = __float_as_uint(v);
    return (x + 0x7fffu + ((x >> 16) & 1u)) >> 16;
}
__device__ __forceinline__ u32 pack2(float lo, float hi) { return bfr(lo) | (bfr(hi) << 16); }
__device__ __forceinline__ float blo(u32 w) { return __uint_as_float(w << 16); }
__device__ __forceinline__ float bhi(u32 w) { return __uint_as_float(w & 0xffff0000u); }

// ---- misc ------------------------------------------------------------------

__global__ void zero_int(int* __restrict__ p, int n) {
    int i = blockIdx.x * blockDim.x + threadIdx.x;
    if (i < n) p[i] = 0;
}

// ---- level-1: bucket histogram of dst>>BKT_SHIFT ---------------------------

__global__ void bucket_hist(const int* __restrict__ dst, int* __restrict__ bucket_cnt,
                            int nE) {
    __shared__ int h[MAXB];
    int t = threadIdx.x;  // 256 threads
    h[t] = 0; h[t + 256] = 0;
    __syncthreads();
    int i0 = blockIdx.x * CHUNK;
    int cn = min(CHUNK, nE - i0);
    for (int i = t; i < cn; i += 256) atomicAdd(&h[dst[i0 + i] >> BKT_SHIFT], 1);
    __syncthreads();
    if (h[t] > 0) atomicAdd(&bucket_cnt[t], h[t]);
    if (h[t + 256] > 0) atomicAdd(&bucket_cnt[t + 256], h[t + 256]);
}

// ---- scan the <=MAXB bucket counts -> base & cursor; row_ptr[n] = nE -------

__global__ void scan_buckets(const int* __restrict__ bucket_cnt, int* __restrict__ bucket_base,
                             int* __restrict__ bucket_cursor, int* __restrict__ row_ptr,
                             int B, int n) {
    __shared__ int s[MAXB];
    int t = threadIdx.x;  // 512 threads
    int v = (t < B) ? bucket_cnt[t] : 0;
    s[t] = v;
    __syncthreads();
    for (int off = 1; off < MAXB; off <<= 1) {
        int u = (t >= off) ? s[t - off] : 0;
        __syncthreads();
        s[t] += u;
        __syncthreads();
    }
    if (t < B) {
        int excl = s[t] - v;
        bucket_base[t] = excl;
        bucket_cursor[t] = excl;
    }
    if (t == MAXB - 1) {
        bucket_base[B] = s[t];   // == nE
        row_ptr[n] = s[t];
    }
}

// ---- level-1 partition: chunk -> in-LDS counting sort -> contiguous runs ---
// Packed word: (dst & (BKT_NODES-1)) << 17 | src     (src < 2^17)

__global__ void partition(const int* __restrict__ src, const int* __restrict__ dst,
                          int* __restrict__ bucket_cursor, int* __restrict__ packed,
                          int nE, int B) {
    __shared__ int hist[MAXB];           // counts, then local cursor
    __shared__ int delta[MAXB];          // global_base - local_excl
    __shared__ int s[MAXB];
    __shared__ int dstb[CHUNK];          // dst chunk buffer (avoid re-read)
    __shared__ int sorted[CHUNK];
    __shared__ unsigned short sortedb[CHUNK];
    int t = threadIdx.x;  // 512 threads
    int i0 = blockIdx.x * CHUNK;
    int cn = min(CHUNK, nE - i0);

    hist[t] = 0;
    __syncthreads();
    for (int i = t; i < cn; i += 512) {
        int d = dst[i0 + i];
        dstb[i] = d;
        atomicAdd(&hist[d >> BKT_SHIFT], 1);
    }
    __syncthreads();

    int v = hist[t];
    s[t] = v;
    __syncthreads();
    for (int off = 1; off < MAXB; off <<= 1) {
        int u = (t >= off) ? s[t - off] : 0;
        __syncthreads();
        s[t] += u;
        __syncthreads();
    }
    {
        int excl = s[t] - v;
        int rb = 0;
        if (t < B && v > 0) rb = atomicAdd(&bucket_cursor[t], v);
        delta[t] = rb - excl;
        hist[t] = excl;   // local cursor for the LDS scatter
    }
    __syncthreads();

    for (int i = t; i < cn; i += 512) {
        int d = dstb[i];
        int b = d >> BKT_SHIFT;
        int pp = atomicAdd(&hist[b], 1);
        sorted[pp]  = ((d & (BKT_NODES - 1)) << 17) | src[i0 + i];
        sortedb[pp] = (unsigned short)b;
    }
    __syncthreads();

    for (int i = t; i < cn; i += 512) {
        packed[delta[sortedb[i]] + i] = sorted[i];
    }
}

// ---- level-2: per-bucket CSR finalize + fused bf16 prescale ----------------
// One block per 256-node bucket: count -> scan -> row_ptr/dinv -> adj scatter,
// then stream F0 = bf16(dinv * x) for the bucket's rows (row = 128 B).

__global__ void bucket_csr(const int* __restrict__ packed, const int* __restrict__ bucket_base,
                           int* __restrict__ row_ptr, float* __restrict__ dinv,
                           int* __restrict__ adj, const float* __restrict__ x,
                           u32* __restrict__ xp, int n) {
    __shared__ int s[BKT_NODES];
    __shared__ int cur[BKT_NODES];
    __shared__ float dv[BKT_NODES];
    int t = threadIdx.x;  // 256 threads
    int b = blockIdx.x;
    int lo = bucket_base[b], hi = bucket_base[b + 1];

    s[t] = 0;
    __syncthreads();
    for (int i = lo + t; i < hi; i += BKT_NODES) atomicAdd(&s[packed[i] >> 17], 1);
    __syncthreads();

    int v = s[t];
    __syncthreads();
    for (int off = 1; off < BKT_NODES; off <<= 1) {
        int u = (t >= off) ? s[t - off] : 0;
        __syncthreads();
        s[t] += u;
        __syncthreads();
    }
    int gbeg = lo + s[t] - v;   // exclusive prefix + bucket base
    int node = (b << BKT_SHIFT) + t;
    float di = rsqrtf(1.0f + (float)v);   // self-loop included
    if (node < n) {
        row_ptr[node] = gbeg;
        dinv[node] = di;
    }
    dv[t] = di;
    cur[t] = gbeg;
    __syncthreads();

    for (int i = lo + t; i < hi; i += BKT_NODES) {
        int w = packed[i];
        int pos = atomicAdd(&cur[w >> 17], 1);
        adj[pos] = w & 0x1FFFF;
    }

    // fused bf16 prescale: thread i -> (row = i>>3, feature block 8*(i&7))
    int base = b << BKT_SHIFT;
    for (int i = t; i < BKT_NODES * 8; i += BKT_NODES) {
        int row = i >> 3, fb = i & 7;
        int nd = base + row;
        if (nd < n) {
            float d2 = dv[row];
            const float4* xr = (const float4*)(x + (size_t)nd * D + 8 * fb);
            float4 v0 = xr[0], v1 = xr[1];
            uint4 w;
            w.x = pack2(d2 * v0.x, d2 * v0.y);
            w.y = pack2(d2 * v0.z, d2 * v0.w);
            w.z = pack2(d2 * v1.x, d2 * v1.y);
            w.w = pack2(d2 * v1.z, d2 * v1.w);
            ((uint4*)(xp + (size_t)nd * (D / 2)))[fb] = w;
        }
    }
}

// ---- pure gather-sum (bf16 rows): S[i] = hp[i] + sum_{s in N(i)} hp[s] -----
// hp rows are bf16 (128 B). One node per 8-lane OCTET (8 nodes/wave); lane f
// holds features 8f..8f+7. One load instruction = 8 rows x 128 B; 8 edges per
// octet per chunk, all 8 row-loads issued back-to-back. fp32 accumulate;
// fp32 S output. Tail edges load row 0 with multiplier 0.
__launch_bounds__(256, 4)
__global__ void agg(const u32* __restrict__ hp, const int* __restrict__ row_ptr,
                    const int* __restrict__ adj, float* __restrict__ S, int n) {
    const int lane = threadIdx.x & 63;
    const int o = lane >> 3;   // octet = which of the wave's 8 nodes
    const int f = lane & 7;    // feature group: features 8f..8f+7
    const int wave = (blockIdx.x * blockDim.x + threadIdx.x) >> 6;
    const int nw = (gridDim.x * blockDim.x) >> 6;

    for (int nb = wave * 8; nb < n; nb += nw * 8) {
        int nq = nb + o;
        bool valid = nq < n;
        int nqc = valid ? nq : 0;
        int rb = row_ptr[nqc];
        int re = row_ptr[nqc + 1];
        int len = valid ? (re - rb) : 0;

        // self-loop term (hp prescaled -> no extra factor)
        uint4 sw = ((const uint4*)(hp + (size_t)nqc * (D / 2)))[f];
        float acc[8];
        acc[0] = blo(sw.x); acc[1] = bhi(sw.x);
        acc[2] = blo(sw.y); acc[3] = bhi(sw.y);
        acc[4] = blo(sw.z); acc[5] = bhi(sw.z);
        acc[6] = blo(sw.w); acc[7] = bhi(sw.w);

        int lm = len;
        lm = max(lm, __shfl_xor(lm, 8, 64));
        lm = max(lm, __shfl_xor(lm, 16, 64));
        lm = max(lm, __shfl_xor(lm, 32, 64));

        for (int base = 0; base < lm; base += 8) {
            int rem = len - base;
            int idx_l = 0;
            if (f < rem) idx_l = adj[rb + base + f];
            int ss[8]; uint4 vv[8];
#pragma unroll
            for (int u = 0; u < 8; ++u) {
                ss[u] = __shfl(idx_l, (o << 3) | u, 64);
            }
#pragma unroll
            for (int u = 0; u < 8; ++u) {
                vv[u] = ((const uint4*)(hp + (size_t)ss[u] * (D / 2)))[f];
            }
#pragma unroll
            for (int u = 0; u < 8; ++u) {
                float m = (u < rem) ? 1.0f : 0.0f;
                acc[0] = fmaf(m, blo(vv[u].x), acc[0]);
                acc[1] = fmaf(m, bhi(vv[u].x), acc[1]);
                acc[2] = fmaf(m, blo(vv[u].y), acc[2]);
                acc[3] = fmaf(m, bhi(vv[u].y), acc[3]);
                acc[4] = fmaf(m, blo(vv[u].z), acc[4]);
                acc[5] = fmaf(m, bhi(vv[u].z), acc[5]);
                acc[6] = fmaf(m, blo(vv[u].w), acc[6]);
                acc[7] = fmaf(m, bhi(vv[u].w), acc[7]);
            }
        }
        if (valid) {
            float4* sp = (float4*)(S + (size_t)nq * D + 8 * f);
            sp[0] = make_float4(acc[0], acc[1], acc[2], acc[3]);
            sp[1] = make_float4(acc[4], acc[5], acc[6], acc[7]);
        }
    }
}

// ---- register-blocked tiled GEMM: out-tile = epi(dinv ⊙ (S_tile @ W)) ------
// MODE 0: Hp(bf16) = dinv * relu(dinv * y)   (pre-scaled layer-1 output)
// MODE 1: out(f32) = dinv * y + bias         (final output)
template <int MODE>
__launch_bounds__(256, 4)
__global__ void tgemm(const float* __restrict__ S, const float* __restrict__ W,
                      const float* __restrict__ bias, const float* __restrict__ dinv,
                      float* __restrict__ outf, u32* __restrict__ outb, int n) {
    __shared__ float Wl[D * D];          // stride 64
    __shared__ float Sl[GROWS * SSTR];   // stride 68 (pad kills pow2 conflicts)
    const int t = threadIdx.x;

    for (int i = t; i < D * D / 4; i += 256)
        ((float4*)Wl)[i] = ((const float4*)W)[i];

    const int R0 = blockIdx.x * GROWS;
    for (int i = t; i < GROWS * 16; i += 256) {
        int row = i >> 4, kq = i & 15;
        float4 v = make_float4(0.f, 0.f, 0.f, 0.f);
        if (R0 + row < n) v = ((const float4*)(S + (size_t)(R0 + row) * D))[kq];
        *(float4*)&Sl[row * SSTR + kq * 4] = v;
    }
    __syncthreads();

    const int cg = t & 15;   // cols 4cg..4cg+3
    const int rg = t >> 4;   // rows 4rg..4rg+3

    float4 acc0 = make_float4(0.f, 0.f, 0.f, 0.f);
    float4 acc1 = make_float4(0.f, 0.f, 0.f, 0.f);
    float4 acc2 = make_float4(0.f, 0.f, 0.f, 0.f);
    float4 acc3 = make_float4(0.f, 0.f, 0.f, 0.f);

#pragma unroll 4
    for (int k = 0; k < D; k += 4) {
        float4 a0 = *(const float4*)&Sl[(4 * rg + 0) * SSTR + k];
        float4 a1 = *(const float4*)&Sl[(4 * rg + 1) * SSTR + k];
        float4 a2 = *(const float4*)&Sl[(4 * rg + 2) * SSTR + k];
        float4 a3 = *(const float4*)&Sl[(4 * rg + 3) * SSTR + k];
        float4 w0 = *(const float4*)&Wl[(k + 0) * D + 4 * cg];
        float4 w1 = *(const float4*)&Wl[(k + 1) * D + 4 * cg];
        float4 w2 = *(const float4*)&Wl[(k + 2) * D + 4 * cg];
        float4 w3 = *(const float4*)&Wl[(k + 3) * D + 4 * cg];
#define MAC(ACC, A)                                                        \
        ACC.x = fmaf(A.x, w0.x, fmaf(A.y, w1.x, fmaf(A.z, w2.x, fmaf(A.w, w3.x, ACC.x)))); \
        ACC.y = fmaf(A.x, w0.y, fmaf(A.y, w1.y, fmaf(A.z, w2.y, fmaf(A.w, w3.y, ACC.y)))); \
        ACC.z = fmaf(A.x, w0.z, fmaf(A.y, w1.z, fmaf(A.z, w2.z, fmaf(A.w, w3.z, ACC.z)))); \
        ACC.w = fmaf(A.x, w0.w, fmaf(A.y, w1.w, fmaf(A.z, w2.w, fmaf(A.w, w3.w, ACC.w))))
        MAC(acc0, a0);
        MAC(acc1, a1);
        MAC(acc2, a2);
        MAC(acc3, a3);
#undef MAC
    }

    const float4 bv = (MODE == 1) ? ((const float4*)bias)[cg]
                                  : make_float4(0.f, 0.f, 0.f, 0.f);
    float4 accs[4] = {acc0, acc1, acc2, acc3};
#pragma unroll
    for (int r = 0; r < 4; ++r) {
        int row = R0 + 4 * rg + r;
        if (row >= n) break;
        float dn = dinv[row];
        float4 y = accs[r];
        if (MODE == 0) {
            float o0 = dn * fmaxf(dn * y.x, 0.f);
            float o1 = dn * fmaxf(dn * y.y, 0.f);
            float o2 = dn * fmaxf(dn * y.z, 0.f);
            float o3 = dn * fmaxf(dn * y.w, 0.f);
            uint2 w2o;
            w2o.x = pack2(o0, o1);
            w2o.y = pack2(o2, o3);
            ((uint2*)(outb + (size_t)row * (D / 2)))[cg] = w2o;
        } else {
            float4 o;
            o.x = fmaf(dn, y.x, bv.x);
            o.y = fmaf(dn, y.y, bv.y);
            o.z = fmaf(dn, y.z, bv.z);
            o.w = fmaf(dn, y.w, bv.w);
            ((float4*)(outf + (size_t)row * D))[cg] = o;
        }
    }
}

// ---- launch ----------------------------------------------------------------

extern "C" void kernel_launch(void* const* d_in, const int* in_sizes, int n_in,
                              void* d_out, int out_size, void* d_ws, size_t ws_size,
                              hipStream_t stream) {
    const float* x  = (const float*)d_in[0];
    const float* W1 = (const float*)d_in[1];
    const float* W2 = (const float*)d_in[2];
    const float* b2 = (const float*)d_in[3];
    const int*   ei = (const int*)d_in[4];

    int n  = in_sizes[0] / D;   // 100000
    int nE = in_sizes[4] / 2;   // 1600000
    const int* src = ei;        // message source
    const int* dst = ei + nE;   // aggregation target

    int B = (n + BKT_NODES - 1) >> BKT_SHIFT;  // 391 buckets (<= MAXB)

    // workspace layout (aligned to 256B):
    //   row_ptr | dinv | bucket_cnt | bucket_base | bucket_cursor | adj |
    //   packed | F0 [n*D/2 u32, bf16] | S [n*D f32]
    auto align = [](size_t v) { return (v + 255) & ~(size_t)255; };
    char* ws = (char*)d_ws;
    size_t off = 0;
    int* row_ptr   = (int*)(ws + off);   off += align((size_t)(n + 1) * 4);
    float* dinv    = (float*)(ws + off); off += align((size_t)n * 4);
    int* bucket_cnt    = (int*)(ws + off); off += align(MAXB * 4);
    int* bucket_base   = (int*)(ws + off); off += align((MAXB + 1) * 4);
    int* bucket_cursor = (int*)(ws + off); off += align(MAXB * 4);
    int* adj       = (int*)(ws + off);   off += align((size_t)nE * 4);
    int* packed    = (int*)(ws + off);   off += align((size_t)nE * 4);
    u32* F0        = (u32*)(ws + off);   off += align((size_t)n * (D / 2) * 4);
    float* Sbuf    = (float*)(ws + off);
    float* out = (float*)d_out;

    int nchunks = (nE + CHUNK - 1) / CHUNK;  // 196

    // CSR build (binned, write-locality preserving) + fused bf16 prescale
    zero_int<<<2, 256, 0, stream>>>(bucket_cnt, MAXB);
    bucket_hist<<<nchunks, 256, 0, stream>>>(dst, bucket_cnt, nE);
    scan_buckets<<<1, MAXB, 0, stream>>>(bucket_cnt, bucket_base, bucket_cursor, row_ptr, B, n);
    partition<<<nchunks, 512, 0, stream>>>(src, dst, bucket_cursor, packed, nE, B);
    bucket_csr<<<B, BKT_NODES, 0, stream>>>(packed, bucket_base, row_ptr, dinv, adj, x, F0, n);

    int gblocks = (n + GROWS - 1) / GROWS;  // 1563

    // layer 1: S = gather(F0) ; F0 = bf16(dinv*relu(dinv*(S@W1)))
    agg<<<1024, 256, 0, stream>>>(F0, row_ptr, adj, Sbuf, n);
    tgemm<0><<<gblocks, 256, 0, stream>>>(Sbuf, W1, nullptr, dinv, nullptr, F0, n);

    // layer 2: S = gather(F0) ; out = dinv*(S@W2) + b2
    agg<<<1024, 256, 0, stream>>>(F0, row_ptr, adj, Sbuf, n);
    tgemm<1><<<gblocks, 256, 0, stream>>>(Sbuf, W2, b2, dinv, out, nullptr, n);
}

// Round 13
// 225.481 us; speedup vs baseline: 1.6140x; 1.0439x over previous
//
#include <hip/hip_runtime.h>

#define D 64
#define CHUNK 8192          // edges per partition block
#define BKT_SHIFT 8         // 256 nodes per bucket
#define BKT_NODES 256
#define MAXB 512            // scan width (B = 391 <= 512)
#define CAP 8192            // fixed region capacity per bucket (mean 4092 + 64 sigma)
#define GROWS 64            // rows per gemm block-tile
#define SSTR 68             // padded LDS row stride for S tile

typedef unsigned int u32;

// bf16 helpers
__device__ __forceinline__ u32 bfr(float v) {          // fp32 -> bf16 bits (RNE)
    u32 x = __float_as_uint(v);
    return (x + 0x7fffu + ((x >> 16) & 1u)) >> 16;
}
__device__ __forceinline__ u32 pack2(float lo, float hi) { return bfr(lo) | (bfr(hi) << 16); }
__device__ __forceinline__ float blo(u32 w) { return __uint_as_float(w << 16); }
__device__ __forceinline__ float bhi(u32 w) { return __uint_as_float(w & 0xffff0000u); }

// ---- init: cursor[b] = b * CAP ---------------------------------------------

__global__ void init_cursor(int* __restrict__ cursor, int B) {
    int i = blockIdx.x * blockDim.x + threadIdx.x;
    if (i < B) cursor[i] = i * CAP;
}

// ---- partition: chunk -> in-LDS counting sort -> contiguous runs into ------
// fixed-capacity bucket regions. Packed word: (dst & 255) << 17 | src.
// No global histogram needed: each block reserves per-bucket runs via one
// atomicAdd on cursor[b] (starts at b*CAP).

__global__ void partition(const int* __restrict__ src, const int* __restrict__ dst,
                          int* __restrict__ cursor, int* __restrict__ packed,
                          int nE, int B) {
    __shared__ int hist[MAXB];           // counts, then local cursor
    __shared__ int delta[MAXB];          // global_run_pos - local_excl
    __shared__ int s[MAXB];
    __shared__ int sorted[CHUNK];
    __shared__ unsigned short sortedb[CHUNK];
    int t = threadIdx.x;  // 512 threads
    int i0 = blockIdx.x * CHUNK;
    int cn = min(CHUNK, nE - i0);

    hist[t] = 0;
    __syncthreads();
    for (int i = t; i < cn; i += 512) atomicAdd(&hist[dst[i0 + i] >> BKT_SHIFT], 1);
    __syncthreads();

    int v = hist[t];
    s[t] = v;
    __syncthreads();
    for (int off = 1; off < MAXB; off <<= 1) {
        int u = (t >= off) ? s[t - off] : 0;
        __syncthreads();
        s[t] += u;
        __syncthreads();
    }
    {
        int excl = s[t] - v;
        int rb = 0;
        if (t < B && v > 0) rb = atomicAdd(&cursor[t], v);
        delta[t] = rb - excl;
        hist[t] = excl;   // local cursor for the LDS scatter
    }
    __syncthreads();

    for (int i = t; i < cn; i += 512) {
        int d = dst[i0 + i];
        int b = d >> BKT_SHIFT;
        int pp = atomicAdd(&hist[b], 1);
        sorted[pp]  = ((d & (BKT_NODES - 1)) << 17) | src[i0 + i];
        sortedb[pp] = (unsigned short)b;
    }
    __syncthreads();

    for (int i = t; i < cn; i += 512) {
        packed[delta[sortedb[i]] + i] = sorted[i];
    }
}

// ---- bucket finalize: in-block bucket_base + per-node CSR + bf16 prescale --
// One block per 256-node bucket. Edges for bucket b live in
// packed[b*CAP .. cursor[b]). bucket_base computed in-block from cursor.

__global__ void bucket_csr(const int* __restrict__ packed, const int* __restrict__ cursor,
                           int* __restrict__ row_ptr, float* __restrict__ dinv,
                           int* __restrict__ adj, const float* __restrict__ x,
                           u32* __restrict__ xp, int n, int B) {
    __shared__ int s[BKT_NODES];
    __shared__ int cur[BKT_NODES];
    __shared__ float dv[BKT_NODES];
    __shared__ int base_s;
    int t = threadIdx.x;  // 256 threads
    int b = blockIdx.x;
    int rlo = b * CAP;
    int mycnt = min(cursor[b] - rlo, CAP);

    // bucket_base[b] = sum of counts of buckets < b  (cursor[i] - i*CAP)
    int partial = 0;
    for (int i = t; i < b; i += BKT_NODES) partial += cursor[i] - i * CAP;
    s[t] = partial;
    __syncthreads();
    for (int off = BKT_NODES / 2; off > 0; off >>= 1) {
        if (t < off) s[t] += s[t + off];
        __syncthreads();
    }
    if (t == 0) base_s = s[0];
    __syncthreads();
    int base = base_s;
    if (b == B - 1 && t == 0) row_ptr[n] = base + mycnt;   // == nE

    // per-node histogram
    s[t] = 0;
    __syncthreads();
    for (int i = t; i < mycnt; i += BKT_NODES) atomicAdd(&s[packed[rlo + i] >> 17], 1);
    __syncthreads();

    int v = s[t];
    __syncthreads();
    for (int off = 1; off < BKT_NODES; off <<= 1) {
        int u = (t >= off) ? s[t - off] : 0;
        __syncthreads();
        s[t] += u;
        __syncthreads();
    }
    int gbeg = base + s[t] - v;   // global exclusive prefix
    int node = (b << BKT_SHIFT) + t;
    float di = rsqrtf(1.0f + (float)v);   // self-loop included
    if (node < n) {
        row_ptr[node] = gbeg;
        dinv[node] = di;
    }
    dv[t] = di;
    cur[t] = gbeg;
    __syncthreads();

    for (int i = t; i < mycnt; i += BKT_NODES) {
        int w = packed[rlo + i];
        int pos = atomicAdd(&cur[w >> 17], 1);
        adj[pos] = w & 0x1FFFF;
    }

    // fused bf16 prescale: thread i -> (row = i>>3, feature block 8*(i&7))
    int nbase = b << BKT_SHIFT;
    for (int i = t; i < BKT_NODES * 8; i += BKT_NODES) {
        int row = i >> 3, fb = i & 7;
        int nd = nbase + row;
        if (nd < n) {
            float d2 = dv[row];
            const float4* xr = (const float4*)(x + (size_t)nd * D + 8 * fb);
            float4 v0 = xr[0], v1 = xr[1];
            uint4 w;
            w.x = pack2(d2 * v0.x, d2 * v0.y);
            w.y = pack2(d2 * v0.z, d2 * v0.w);
            w.z = pack2(d2 * v1.x, d2 * v1.y);
            w.w = pack2(d2 * v1.z, d2 * v1.w);
            ((uint4*)(xp + (size_t)nd * (D / 2)))[fb] = w;
        }
    }
}

// ---- pure gather-sum (bf16 rows): S[i] = hp[i] + sum_{s in N(i)} hp[s] -----
__launch_bounds__(256, 4)
__global__ void agg(const u32* __restrict__ hp, const int* __restrict__ row_ptr,
                    const int* __restrict__ adj, float* __restrict__ S, int n) {
    const int lane = threadIdx.x & 63;
    const int o = lane >> 3;   // octet = which of the wave's 8 nodes
    const int f = lane & 7;    // feature group: features 8f..8f+7
    const int wave = (blockIdx.x * blockDim.x + threadIdx.x) >> 6;
    const int nw = (gridDim.x * blockDim.x) >> 6;

    for (int nb = wave * 8; nb < n; nb += nw * 8) {
        int nq = nb + o;
        bool valid = nq < n;
        int nqc = valid ? nq : 0;
        int rb = row_ptr[nqc];
        int re = row_ptr[nqc + 1];
        int len = valid ? (re - rb) : 0;

        uint4 sw = ((const uint4*)(hp + (size_t)nqc * (D / 2)))[f];
        float acc[8];
        acc[0] = blo(sw.x); acc[1] = bhi(sw.x);
        acc[2] = blo(sw.y); acc[3] = bhi(sw.y);
        acc[4] = blo(sw.z); acc[5] = bhi(sw.z);
        acc[6] = blo(sw.w); acc[7] = bhi(sw.w);

        int lm = len;
        lm = max(lm, __shfl_xor(lm, 8, 64));
        lm = max(lm, __shfl_xor(lm, 16, 64));
        lm = max(lm, __shfl_xor(lm, 32, 64));

        for (int base = 0; base < lm; base += 8) {
            int rem = len - base;
            int idx_l = 0;
            if (f < rem) idx_l = adj[rb + base + f];
            int ss[8]; uint4 vv[8];
#pragma unroll
            for (int u = 0; u < 8; ++u) {
                ss[u] = __shfl(idx_l, (o << 3) | u, 64);
            }
#pragma unroll
            for (int u = 0; u < 8; ++u) {
                vv[u] = ((const uint4*)(hp + (size_t)ss[u] * (D / 2)))[f];
            }
#pragma unroll
            for (int u = 0; u < 8; ++u) {
                float m = (u < rem) ? 1.0f : 0.0f;
                acc[0] = fmaf(m, blo(vv[u].x), acc[0]);
                acc[1] = fmaf(m, bhi(vv[u].x), acc[1]);
                acc[2] = fmaf(m, blo(vv[u].y), acc[2]);
                acc[3] = fmaf(m, bhi(vv[u].y), acc[3]);
                acc[4] = fmaf(m, blo(vv[u].z), acc[4]);
                acc[5] = fmaf(m, bhi(vv[u].z), acc[5]);
                acc[6] = fmaf(m, blo(vv[u].w), acc[6]);
                acc[7] = fmaf(m, bhi(vv[u].w), acc[7]);
            }
        }
        if (valid) {
            float4* sp = (float4*)(S + (size_t)nq * D + 8 * f);
            sp[0] = make_float4(acc[0], acc[1], acc[2], acc[3]);
            sp[1] = make_float4(acc[4], acc[5], acc[6], acc[7]);
        }
    }
}

// ---- register-blocked tiled GEMM: out-tile = epi(dinv ⊙ (S_tile @ W)) ------
// MODE 0: Hp(bf16) = dinv * relu(dinv * y)   (pre-scaled layer-1 output)
// MODE 1: out(f32) = dinv * y + bias         (final output)
template <int MODE>
__launch_bounds__(256, 4)
__global__ void tgemm(const float* __restrict__ S, const float* __restrict__ W,
                      const float* __restrict__ bias, const float* __restrict__ dinv,
                      float* __restrict__ outf, u32* __restrict__ outb, int n) {
    __shared__ float Wl[D * D];          // stride 64
    __shared__ float Sl[GROWS * SSTR];   // stride 68 (pad kills pow2 conflicts)
    const int t = threadIdx.x;

    for (int i = t; i < D * D / 4; i += 256)
        ((float4*)Wl)[i] = ((const float4*)W)[i];

    const int R0 = blockIdx.x * GROWS;
    for (int i = t; i < GROWS * 16; i += 256) {
        int row = i >> 4, kq = i & 15;
        float4 v = make_float4(0.f, 0.f, 0.f, 0.f);
        if (R0 + row < n) v = ((const float4*)(S + (size_t)(R0 + row) * D))[kq];
        *(float4*)&Sl[row * SSTR + kq * 4] = v;
    }
    __syncthreads();

    const int cg = t & 15;   // cols 4cg..4cg+3
    const int rg = t >> 4;   // rows 4rg..4rg+3

    float4 acc0 = make_float4(0.f, 0.f, 0.f, 0.f);
    float4 acc1 = make_float4(0.f, 0.f, 0.f, 0.f);
    float4 acc2 = make_float4(0.f, 0.f, 0.f, 0.f);
    float4 acc3 = make_float4(0.f, 0.f, 0.f, 0.f);

#pragma unroll 4
    for (int k = 0; k < D; k += 4) {
        float4 a0 = *(const float4*)&Sl[(4 * rg + 0) * SSTR + k];
        float4 a1 = *(const float4*)&Sl[(4 * rg + 1) * SSTR + k];
        float4 a2 = *(const float4*)&Sl[(4 * rg + 2) * SSTR + k];
        float4 a3 = *(const float4*)&Sl[(4 * rg + 3) * SSTR + k];
        float4 w0 = *(const float4*)&Wl[(k + 0) * D + 4 * cg];
        float4 w1 = *(const float4*)&Wl[(k + 1) * D + 4 * cg];
        float4 w2 = *(const float4*)&Wl[(k + 2) * D + 4 * cg];
        float4 w3 = *(const float4*)&Wl[(k + 3) * D + 4 * cg];
#define MAC(ACC, A)                                                        \
        ACC.x = fmaf(A.x, w0.x, fmaf(A.y, w1.x, fmaf(A.z, w2.x, fmaf(A.w, w3.x, ACC.x)))); \
        ACC.y = fmaf(A.x, w0.y, fmaf(A.y, w1.y, fmaf(A.z, w2.y, fmaf(A.w, w3.y, ACC.y)))); \
        ACC.z = fmaf(A.x, w0.z, fmaf(A.y, w1.z, fmaf(A.z, w2.z, fmaf(A.w, w3.z, ACC.z)))); \
        ACC.w = fmaf(A.x, w0.w, fmaf(A.y, w1.w, fmaf(A.z, w2.w, fmaf(A.w, w3.w, ACC.w))))
        MAC(acc0, a0);
        MAC(acc1, a1);
        MAC(acc2, a2);
        MAC(acc3, a3);
#undef MAC
    }

    const float4 bv = (MODE == 1) ? ((const float4*)bias)[cg]
                                  : make_float4(0.f, 0.f, 0.f, 0.f);
    float4 accs[4] = {acc0, acc1, acc2, acc3};
#pragma unroll
    for (int r = 0; r < 4; ++r) {
        int row = R0 + 4 * rg + r;
        if (row >= n) break;
        float dn = dinv[row];
        float4 y = accs[r];
        if (MODE == 0) {
            float o0 = dn * fmaxf(dn * y.x, 0.f);
            float o1 = dn * fmaxf(dn * y.y, 0.f);
            float o2 = dn * fmaxf(dn * y.z, 0.f);
            float o3 = dn * fmaxf(dn * y.w, 0.f);
            uint2 w2o;
            w2o.x = pack2(o0, o1);
            w2o.y = pack2(o2, o3);
            ((uint2*)(outb + (size_t)row * (D / 2)))[cg] = w2o;
        } else {
            float4 o;
            o.x = fmaf(dn, y.x, bv.x);
            o.y = fmaf(dn, y.y, bv.y);
            o.z = fmaf(dn, y.z, bv.z);
            o.w = fmaf(dn, y.w, bv.w);
            ((float4*)(outf + (size_t)row * D))[cg] = o;
        }
    }
}

// ---- launch ----------------------------------------------------------------

extern "C" void kernel_launch(void* const* d_in, const int* in_sizes, int n_in,
                              void* d_out, int out_size, void* d_ws, size_t ws_size,
                              hipStream_t stream) {
    const float* x  = (const float*)d_in[0];
    const float* W1 = (const float*)d_in[1];
    const float* W2 = (const float*)d_in[2];
    const float* b2 = (const float*)d_in[3];
    const int*   ei = (const int*)d_in[4];

    int n  = in_sizes[0] / D;   // 100000
    int nE = in_sizes[4] / 2;   // 1600000
    const int* src = ei;        // message source
    const int* dst = ei + nE;   // aggregation target

    int B = (n + BKT_NODES - 1) >> BKT_SHIFT;  // 391 buckets

    // workspace layout (aligned to 256B):
    //   row_ptr | dinv | cursor [B] | adj [nE] | packed [(B+1)*CAP] |
    //   F0 [n*D/2 u32, bf16] | S [n*D f32]
    auto align = [](size_t v) { return (v + 255) & ~(size_t)255; };
    char* ws = (char*)d_ws;
    size_t off = 0;
    int* row_ptr = (int*)(ws + off);   off += align((size_t)(n + 1) * 4);
    float* dinv  = (float*)(ws + off); off += align((size_t)n * 4);
    int* cursor  = (int*)(ws + off);   off += align((size_t)MAXB * 4);
    int* adj     = (int*)(ws + off);   off += align((size_t)nE * 4);
    int* packed  = (int*)(ws + off);   off += align((size_t)(B + 1) * CAP * 4);
    u32* F0      = (u32*)(ws + off);   off += align((size_t)n * (D / 2) * 4);
    float* Sbuf  = (float*)(ws + off);
    float* out = (float*)d_out;

    int nchunks = (nE + CHUNK - 1) / CHUNK;  // 196

    // CSR build: 3 dispatches
    init_cursor<<<2, 256, 0, stream>>>(cursor, B);
    partition<<<nchunks, 512, 0, stream>>>(src, dst, cursor, packed, nE, B);
    bucket_csr<<<B, BKT_NODES, 0, stream>>>(packed, cursor, row_ptr, dinv, adj, x, F0, n, B);

    int gblocks = (n + GROWS - 1) / GROWS;  // 1563

    // layer 1: S = gather(F0) ; F0 = bf16(dinv*relu(dinv*(S@W1)))
    agg<<<1024, 256, 0, stream>>>(F0, row_ptr, adj, Sbuf, n);
    tgemm<0><<<gblocks, 256, 0, stream>>>(Sbuf, W1, nullptr, dinv, nullptr, F0, n);

    // layer 2: S = gather(F0) ; out = dinv*(S@W2) + b2
    agg<<<1024, 256, 0, stream>>>(F0, row_ptr, adj, Sbuf, n);
    tgemm<1><<<gblocks, 256, 0, stream>>>(Sbuf, W2, b2, dinv, out, nullptr, n);
}